// Round 3
// baseline (529.631 us; speedup 1.0000x reference)
//
#include <hip/hip_runtime.h>
#include <hip/hip_cooperative_groups.h>

typedef unsigned int u32;
typedef unsigned short u16;
typedef __bf16 bf16x8 __attribute__((ext_vector_type(8)));
typedef float f32x4 __attribute__((ext_vector_type(4)));

#define D 2048           // D_IN == D_MODEL == S == 2048
#define BATCH 2
#define BM 256
#define BN 128
#define BK 64
#define NT (D / BK)          // 32 K-tiles
#define ABUF (BM * BK)       // 16384 u16 = 32 KB
#define BBUF (BN * BK)       // 8192  u16 = 16 KB
#define BUFSZ (ABUF + BBUF)  // 24576 u16 = 48 KB per buffer, x3 = 144 KB

// ---------- helpers ----------
__device__ __forceinline__ u32 bf16rne(float f) {
  u32 u = __builtin_bit_cast(u32, f);
  return (u + 0x7fffu + ((u >> 16) & 1u)) >> 16;
}
__device__ __forceinline__ u32 pk2(float lo, float hi) {
  return bf16rne(lo) | (bf16rne(hi) << 16);
}
__device__ __forceinline__ void async16(const u16* g, u16* l) {
  __builtin_amdgcn_global_load_lds(
      (const __attribute__((address_space(1))) void*)g,
      (__attribute__((address_space(3))) void*)l, 16, 0, 0);
}

// ---------- single fused kernel: prep (x->bf16, wt build) -> grid sync -> GEMM ----------
// Cooperative launch, 256 blocks x 512 threads, 144 KB dynamic LDS => exactly
// 1 block/CU on 256 CUs, all co-resident (required for grid.sync()).
__global__ void __launch_bounds__(512, 2)
fused_kernel(const float* __restrict__ x, u16* __restrict__ xb,
             const float* __restrict__ W, const int* __restrict__ sidx,
             const float* __restrict__ sprob, u16* __restrict__ wt,
             const float* __restrict__ bias, float* __restrict__ out) {
  extern __shared__ __align__(16) u16 LL[];

  const int tid = threadIdx.x;
  const int gtid = blockIdx.x * 512 + tid;  // 0..131071

  // ===== phase A1: xb = bf16(x), 8 x uint4-units per thread, coalesced =====
  {
    const float4* x4 = (const float4*)x;
    uint4* xo = (uint4*)xb;
#pragma unroll
    for (int it = 0; it < 8; ++it) {
      size_t u = (size_t)it * 131072 + gtid;
      float4 a = x4[2 * u], c = x4[2 * u + 1];
      xo[u] = make_uint4(pk2(a.x, a.y), pk2(a.z, a.w),
                         pk2(c.x, c.y), pk2(c.z, c.w));
    }
  }

  // ===== phase A2: wt[b][n][k] = bf16(p0*W[i0][k][n] + p1*W[i1][k][n]) =====
  // 1 unit/thread: an n-pair (float2 loads, 8B/lane) x 32 k values.
  {
    const int u = gtid;
    const int b = u >> 16;                 // 131072 units = 2 b x 64 k0 x 1024 n-pairs
    const int k0 = ((u >> 10) & 63) * 32;
    const int n = (u & 1023) * 2;
    const int i0 = sidx[2 * b], i1 = sidx[2 * b + 1];
    const float p0 = sprob[2 * b], p1 = sprob[2 * b + 1];
    const float* w0 = W + ((size_t)i0 * D + k0) * D + n;
    const float* w1 = W + ((size_t)i1 * D + k0) * D + n;
    u32 re[16], ro[16];
#pragma unroll
    for (int j = 0; j < 16; ++j) {
      float2 a0 = *(const float2*)&w0[(size_t)(2 * j) * D];
      float2 c0 = *(const float2*)&w1[(size_t)(2 * j) * D];
      float2 a1 = *(const float2*)&w0[(size_t)(2 * j + 1) * D];
      float2 c1 = *(const float2*)&w1[(size_t)(2 * j + 1) * D];
      re[j] = pk2(p0 * a0.x + p1 * c0.x, p0 * a1.x + p1 * c1.x);
      ro[j] = pk2(p0 * a0.y + p1 * c0.y, p0 * a1.y + p1 * c1.y);
    }
    uint4* de = (uint4*)(wt + ((size_t)b * D + n) * D + k0);
    uint4* dodd = (uint4*)(wt + ((size_t)b * D + n + 1) * D + k0);
#pragma unroll
    for (int qq = 0; qq < 4; ++qq) {
      de[qq]   = make_uint4(re[4 * qq], re[4 * qq + 1], re[4 * qq + 2], re[4 * qq + 3]);
      dodd[qq] = make_uint4(ro[4 * qq], ro[4 * qq + 1], ro[4 * qq + 2], ro[4 * qq + 3]);
    }
  }

  __threadfence();
  cooperative_groups::this_grid().sync();

  // ===== phase B: out[b] = xb[b] @ wt[b]^T + bsel[b] (round-2 verified GEMM) =====
  // XCD swizzle: consecutive blockIdx round-robin XCDs; contiguous swz-chunk per
  // XCD => blocks sharing an A-panel colocate on one XCD's L2.
  const int fid = blockIdx.x;                  // 0..255
  const int swz = (fid & 7) * 32 + (fid >> 3); // bijective (256 % 8 == 0)
  const int b   = swz >> 7;                    // batch
  const int rem = swz & 127;
  const int m0 = (rem >> 4) * BM;              // 8 m-blocks
  const int n0 = (rem & 15) * BN;              // 16 n-blocks share A-panel

  const int lane = tid & 63;
  const int wid  = tid >> 6;
  const int wm = (wid >> 1) * 64;   // 4 wave-rows over 256 m
  const int wn = (wid & 1) * 64;    // 2 wave-cols over 128 n
  const int fm = lane & 15;
  const int q  = lane >> 4;         // 16B k-chunk index within a 32-k plane

  const u16* Ab = xb + (size_t)b * D * D;
  const u16* Bb = wt + (size_t)b * D * D;

  // staging: inst i covers granules g = i*512 + tid; LDS dest linear, XOR
  // swizzle applied on the SOURCE k-chunk (both-sides-or-neither rule).
  const int srow  = tid >> 3;
  const int sslot = (tid & 7) ^ (srow & 7);
  const u16* srcp[6];
#pragma unroll
  for (int i = 0; i < 4; ++i)
    srcp[i] = Ab + (size_t)(m0 + i * 64 + srow) * D + sslot * 8;
#pragma unroll
  for (int i = 0; i < 2; ++i)
    srcp[4 + i] = Bb + (size_t)(n0 + i * 64 + srow) * D + sslot * 8;

  const int wuni = (tid & ~63) * 8;  // wave-uniform LDS granule base (elems)

  auto stageInst = [&](int buf, int i) {
    async16(srcp[i], LL + buf * BUFSZ + i * 4096 + wuni);
  };

  // fragment read offsets (elements), XOR-swizzled to match staged layout
  int offA[4][2], offB[4][2];
#pragma unroll
  for (int m = 0; m < 4; ++m) {
    const int row = wm + m * 16 + fm;
#pragma unroll
    for (int ks = 0; ks < 2; ++ks)
      offA[m][ks] = row * 64 + (((ks * 4 + q) ^ (row & 7)) * 8);
  }
#pragma unroll
  for (int n = 0; n < 4; ++n) {
    const int row = wn + n * 16 + fm;
#pragma unroll
    for (int ks = 0; ks < 2; ++ks)
      offB[n][ks] = ABUF + row * 64 + (((ks * 4 + q) ^ (row & 7)) * 8);
  }

  f32x4 acc[4][4] = {};

  // prologue: stage tiles 0,1 into bufs 0,1; wait only for tile 0
#pragma unroll
  for (int i = 0; i < 6; ++i) stageInst(0, i);
#pragma unroll
  for (int i = 0; i < 6; ++i) srcp[i] += BK;
#pragma unroll
  for (int i = 0; i < 6; ++i) stageInst(1, i);
#pragma unroll
  for (int i = 0; i < 6; ++i) srcp[i] += BK;
  asm volatile("s_waitcnt vmcnt(6)" ::: "memory");
  __builtin_amdgcn_s_barrier();

  int cur = 0;
#pragma unroll 1
  for (int t = 0; t < NT; ++t) {
    const u16* Lc = LL + cur * BUFSZ;
    int nst = cur + 2; if (nst >= 3) nst -= 3;
    const bool doStage = (t + 2 < NT);

    bf16x8 af[4], bfr[4];

    // ---- phase 0 (ks = 0) ----
#pragma unroll
    for (int m = 0; m < 4; ++m) af[m]  = *(const bf16x8*)(Lc + offA[m][0]);
#pragma unroll
    for (int n = 0; n < 4; ++n) bfr[n] = *(const bf16x8*)(Lc + offB[n][0]);
    if (doStage) { stageInst(nst, 0); stageInst(nst, 1); stageInst(nst, 2); }
    __builtin_amdgcn_s_barrier();
    asm volatile("s_waitcnt lgkmcnt(0)" ::: "memory");
    __builtin_amdgcn_sched_barrier(0);
    __builtin_amdgcn_s_setprio(1);
#pragma unroll
    for (int m = 0; m < 4; ++m)
#pragma unroll
      for (int n = 0; n < 4; ++n)
        acc[m][n] = __builtin_amdgcn_mfma_f32_16x16x32_bf16(af[m], bfr[n],
                                                            acc[m][n], 0, 0, 0);
    __builtin_amdgcn_s_setprio(0);

    // ---- phase 1 (ks = 1), no barrier vs phase 0: no intra-iter hazard ----
#pragma unroll
    for (int m = 0; m < 4; ++m) af[m]  = *(const bf16x8*)(Lc + offA[m][1]);
#pragma unroll
    for (int n = 0; n < 4; ++n) bfr[n] = *(const bf16x8*)(Lc + offB[n][1]);
    if (doStage) { stageInst(nst, 3); stageInst(nst, 4); stageInst(nst, 5); }
    __builtin_amdgcn_s_barrier();
    asm volatile("s_waitcnt lgkmcnt(0)" ::: "memory");
    __builtin_amdgcn_sched_barrier(0);
    __builtin_amdgcn_s_setprio(1);
#pragma unroll
    for (int m = 0; m < 4; ++m)
#pragma unroll
      for (int n = 0; n < 4; ++n)
        acc[m][n] = __builtin_amdgcn_mfma_f32_16x16x32_bf16(af[m], bfr[n],
                                                            acc[m][n], 0, 0, 0);
    __builtin_amdgcn_s_setprio(0);
#pragma unroll
    for (int i = 0; i < 6; ++i) srcp[i] += BK;
    // counted wait: NEXT tile's 6 loads landed; newest 6 stay in flight
    if (t < NT - 2) asm volatile("s_waitcnt vmcnt(6)" ::: "memory");
    else            asm volatile("s_waitcnt vmcnt(0)" ::: "memory");
    __builtin_amdgcn_s_barrier();

    cur = (cur + 1 >= 3) ? 0 : cur + 1;
  }

  // epilogue: C/D layout col=lane&15, row=(lane>>4)*4+reg; fuse bias superposition
  const int i0 = sidx[2 * b], i1 = sidx[2 * b + 1];
  const float p0 = sprob[2 * b], p1 = sprob[2 * b + 1];
  const int rq = q * 4;
  float* Ob = out + (size_t)b * D * D;
#pragma unroll
  for (int n = 0; n < 4; ++n) {
    const int colg = n0 + wn + n * 16 + fm;
    const float bs = p0 * bias[i0 * D + colg] + p1 * bias[i1 * D + colg];
#pragma unroll
    for (int m = 0; m < 4; ++m) {
      const int rowb = m0 + wm + m * 16 + rq;
#pragma unroll
      for (int r = 0; r < 4; ++r)
        Ob[(size_t)(rowb + r) * D + colg] = acc[m][n][r] + bs;
    }
  }
}

extern "C" void kernel_launch(void* const* d_in, const int* in_sizes, int n_in,
                              void* d_out, int out_size, void* d_ws, size_t ws_size,
                              hipStream_t stream) {
  const float* tensor = (const float*)d_in[0];   // (2,2048,16,128) fp32
  const int*   sidx   = (const int*)d_in[1];     // (2,2) int32
  const float* sprob  = (const float*)d_in[2];   // (2,2) fp32
  const float* weight = (const float*)d_in[3];   // (16,2048,2048) fp32
  const float* bias   = (const float*)d_in[4];   // (16,2048) fp32
  float* out = (float*)d_out;                    // (2,2048,2048) fp32

  u16* xb = (u16*)d_ws;                          // (2,2048,2048) bf16, 16 MB
  u16* wt = xb + (size_t)BATCH * D * D;          // (2,2048,2048) bf16, 16 MB

  static bool inited = false;
  if (!inited) {
    (void)hipFuncSetAttribute((const void*)fused_kernel,
                              hipFuncAttributeMaxDynamicSharedMemorySize,
                              3 * BUFSZ * 2);
    inited = true;
  }

  void* args[8] = {(void*)&tensor, (void*)&xb, (void*)&weight, (void*)&sidx,
                   (void*)&sprob, (void*)&wt, (void*)&bias, (void*)&out};
  (void)hipLaunchCooperativeKernel((void*)fused_kernel, dim3(256), dim3(512),
                                   args, 3 * BUFSZ * 2, stream);
}

// Round 4
// 389.712 us; speedup vs baseline: 1.3590x; 1.3590x over previous
//
#include <hip/hip_runtime.h>

typedef unsigned int u32;
typedef unsigned short u16;
typedef __bf16 bf16x8 __attribute__((ext_vector_type(8)));
typedef float f32x4 __attribute__((ext_vector_type(4)));

#define D 2048           // D_IN == D_MODEL == S == 2048
#define BATCH 2
#define BM 256
#define BN 128
#define BK 64
#define NT (D / BK)          // 32 K-tiles
#define ABUF (BM * BK)       // 16384 u16 = 32 KB
#define BBUF (BN * BK)       // 8192  u16 = 16 KB
#define BUFSZ (ABUF + BBUF)  // 24576 u16 = 48 KB per buffer, x3 = 144 KB

// ---------- helpers ----------
__device__ __forceinline__ u32 bf16rne(float f) {
  u32 u = __builtin_bit_cast(u32, f);
  return (u + 0x7fffu + ((u >> 16) & 1u)) >> 16;
}
__device__ __forceinline__ u32 pk2(float lo, float hi) {
  return bf16rne(lo) | (bf16rne(hi) << 16);
}
__device__ __forceinline__ void async16(const u16* g, u16* l) {
  __builtin_amdgcn_global_load_lds(
      (const __attribute__((address_space(1))) void*)g,
      (__attribute__((address_space(3))) void*)l, 16, 0, 0);
}

// ---------- merged prep (high-occupancy, 256-thread blocks, no LDS) ----------
// blocks [0,4096): xb = bf16(x), 8 elems/thread, coalesced.
// blocks [4096,4608): wt[b][n][k] = bf16(p0*W[i0][k][n] + p1*W[i1][k][n]),
//   one n-PAIR per thread (float2 loads, verified in round 3's refcheck).
__global__ void __launch_bounds__(256) prep_kernel(const float* __restrict__ x,
                                                   u16* __restrict__ xb,
                                                   const float* __restrict__ W,
                                                   const int* __restrict__ sidx,
                                                   const float* __restrict__ sprob,
                                                   u16* __restrict__ wt) {
  if (blockIdx.x < 4096) {
    size_t t = (size_t)blockIdx.x * 256 + threadIdx.x;
    const float4* x4 = (const float4*)x;
    float4 a = x4[2 * t], c = x4[2 * t + 1];
    ((uint4*)xb)[t] = make_uint4(pk2(a.x, a.y), pk2(a.z, a.w),
                                 pk2(c.x, c.y), pk2(c.z, c.w));
  } else {
    const int u = (blockIdx.x - 4096) * 256 + threadIdx.x;  // 0..131071
    const int b = u >> 16;                 // 2 b x 64 k0 x 1024 n-pairs
    const int k0 = ((u >> 10) & 63) * 32;
    const int n = (u & 1023) * 2;
    const int i0 = sidx[2 * b], i1 = sidx[2 * b + 1];
    const float p0 = sprob[2 * b], p1 = sprob[2 * b + 1];
    const float* w0 = W + ((size_t)i0 * D + k0) * D + n;
    const float* w1 = W + ((size_t)i1 * D + k0) * D + n;
    u32 re[16], ro[16];
#pragma unroll
    for (int j = 0; j < 16; ++j) {
      float2 a0 = *(const float2*)&w0[(size_t)(2 * j) * D];
      float2 c0 = *(const float2*)&w1[(size_t)(2 * j) * D];
      float2 a1 = *(const float2*)&w0[(size_t)(2 * j + 1) * D];
      float2 c1 = *(const float2*)&w1[(size_t)(2 * j + 1) * D];
      re[j] = pk2(p0 * a0.x + p1 * c0.x, p0 * a1.x + p1 * c1.x);
      ro[j] = pk2(p0 * a0.y + p1 * c0.y, p0 * a1.y + p1 * c1.y);
    }
    uint4* de = (uint4*)(wt + ((size_t)b * D + n) * D + k0);
    uint4* dodd = (uint4*)(wt + ((size_t)b * D + n + 1) * D + k0);
#pragma unroll
    for (int qq = 0; qq < 4; ++qq) {
      de[qq]   = make_uint4(re[4 * qq], re[4 * qq + 1], re[4 * qq + 2], re[4 * qq + 3]);
      dodd[qq] = make_uint4(ro[4 * qq], ro[4 * qq + 1], ro[4 * qq + 2], ro[4 * qq + 3]);
    }
  }
}

// ---------- kernel 2: out[b] = xb[b] @ wt[b]^T + bsel[b] (round-2 verified, 382.4 us) ----------
// 256x128 tile, BK=64, 512 threads = 8 waves (4M x 2N), per-wave 64x64 output.
// Triple-buffered LDS (144 KB), counted vmcnt(6) (never drained in-loop),
// XOR-swizzled k-chunks (pre-swizzled global source + linear global_load_lds
// dest + swizzled ds_read), setprio around MFMA, XCD-aware block swizzle.
__global__ void __launch_bounds__(512, 2)
gemm_kernel(const u16* __restrict__ xb, const u16* __restrict__ wt,
            const float* __restrict__ bias, const int* __restrict__ sidx,
            const float* __restrict__ sprob, float* __restrict__ out) {
  extern __shared__ __align__(16) u16 LL[];

  const int fid = blockIdx.x;                  // 0..255
  const int swz = (fid & 7) * 32 + (fid >> 3); // bijective (256 % 8 == 0)
  const int b   = swz >> 7;                    // batch
  const int rem = swz & 127;
  const int m0 = (rem >> 4) * BM;              // 8 m-blocks
  const int n0 = (rem & 15) * BN;              // 16 n-blocks share A-panel

  const int tid  = threadIdx.x;
  const int lane = tid & 63;
  const int wid  = tid >> 6;
  const int wm = (wid >> 1) * 64;   // 4 wave-rows over 256 m
  const int wn = (wid & 1) * 64;    // 2 wave-cols over 128 n
  const int fm = lane & 15;
  const int q  = lane >> 4;         // 16B k-chunk index within a 32-k plane

  const u16* Ab = xb + (size_t)b * D * D;
  const u16* Bb = wt + (size_t)b * D * D;

  const int srow  = tid >> 3;
  const int sslot = (tid & 7) ^ (srow & 7);
  const u16* srcp[6];
#pragma unroll
  for (int i = 0; i < 4; ++i)
    srcp[i] = Ab + (size_t)(m0 + i * 64 + srow) * D + sslot * 8;
#pragma unroll
  for (int i = 0; i < 2; ++i)
    srcp[4 + i] = Bb + (size_t)(n0 + i * 64 + srow) * D + sslot * 8;

  const int wuni = (tid & ~63) * 8;  // wave-uniform LDS granule base (elems)

  auto stageInst = [&](int buf, int i) {
    async16(srcp[i], LL + buf * BUFSZ + i * 4096 + wuni);
  };

  int offA[4][2], offB[4][2];
#pragma unroll
  for (int m = 0; m < 4; ++m) {
    const int row = wm + m * 16 + fm;
#pragma unroll
    for (int ks = 0; ks < 2; ++ks)
      offA[m][ks] = row * 64 + (((ks * 4 + q) ^ (row & 7)) * 8);
  }
#pragma unroll
  for (int n = 0; n < 4; ++n) {
    const int row = wn + n * 16 + fm;
#pragma unroll
    for (int ks = 0; ks < 2; ++ks)
      offB[n][ks] = ABUF + row * 64 + (((ks * 4 + q) ^ (row & 7)) * 8);
  }

  f32x4 acc[4][4] = {};

#pragma unroll
  for (int i = 0; i < 6; ++i) stageInst(0, i);
#pragma unroll
  for (int i = 0; i < 6; ++i) srcp[i] += BK;
#pragma unroll
  for (int i = 0; i < 6; ++i) stageInst(1, i);
#pragma unroll
  for (int i = 0; i < 6; ++i) srcp[i] += BK;
  asm volatile("s_waitcnt vmcnt(6)" ::: "memory");
  __builtin_amdgcn_s_barrier();

  int cur = 0;
#pragma unroll 1
  for (int t = 0; t < NT; ++t) {
    const u16* Lc = LL + cur * BUFSZ;
    int nst = cur + 2; if (nst >= 3) nst -= 3;
    const bool doStage = (t + 2 < NT);

    bf16x8 af[4], bfr[4];

    // ---- phase 0 (ks = 0) ----
#pragma unroll
    for (int m = 0; m < 4; ++m) af[m]  = *(const bf16x8*)(Lc + offA[m][0]);
#pragma unroll
    for (int n = 0; n < 4; ++n) bfr[n] = *(const bf16x8*)(Lc + offB[n][0]);
    if (doStage) { stageInst(nst, 0); stageInst(nst, 1); stageInst(nst, 2); }
    __builtin_amdgcn_s_barrier();
    asm volatile("s_waitcnt lgkmcnt(0)" ::: "memory");
    __builtin_amdgcn_sched_barrier(0);
    __builtin_amdgcn_s_setprio(1);
#pragma unroll
    for (int m = 0; m < 4; ++m)
#pragma unroll
      for (int n = 0; n < 4; ++n)
        acc[m][n] = __builtin_amdgcn_mfma_f32_16x16x32_bf16(af[m], bfr[n],
                                                            acc[m][n], 0, 0, 0);
    __builtin_amdgcn_s_setprio(0);

    // ---- phase 1 (ks = 1), no barrier vs phase 0: no intra-iter hazard ----
#pragma unroll
    for (int m = 0; m < 4; ++m) af[m]  = *(const bf16x8*)(Lc + offA[m][1]);
#pragma unroll
    for (int n = 0; n < 4; ++n) bfr[n] = *(const bf16x8*)(Lc + offB[n][1]);
    if (doStage) { stageInst(nst, 3); stageInst(nst, 4); stageInst(nst, 5); }
    __builtin_amdgcn_s_barrier();
    asm volatile("s_waitcnt lgkmcnt(0)" ::: "memory");
    __builtin_amdgcn_sched_barrier(0);
    __builtin_amdgcn_s_setprio(1);
#pragma unroll
    for (int m = 0; m < 4; ++m)
#pragma unroll
      for (int n = 0; n < 4; ++n)
        acc[m][n] = __builtin_amdgcn_mfma_f32_16x16x32_bf16(af[m], bfr[n],
                                                            acc[m][n], 0, 0, 0);
    __builtin_amdgcn_s_setprio(0);
#pragma unroll
    for (int i = 0; i < 6; ++i) srcp[i] += BK;
    if (t < NT - 2) asm volatile("s_waitcnt vmcnt(6)" ::: "memory");
    else            asm volatile("s_waitcnt vmcnt(0)" ::: "memory");
    __builtin_amdgcn_s_barrier();

    cur = (cur + 1 >= 3) ? 0 : cur + 1;
  }

  // epilogue: C/D layout col=lane&15, row=(lane>>4)*4+reg; fuse bias superposition
  const int i0 = sidx[2 * b], i1 = sidx[2 * b + 1];
  const float p0 = sprob[2 * b], p1 = sprob[2 * b + 1];
  const int rq = q * 4;
  float* Ob = out + (size_t)b * D * D;
#pragma unroll
  for (int n = 0; n < 4; ++n) {
    const int colg = n0 + wn + n * 16 + fm;
    const float bs = p0 * bias[i0 * D + colg] + p1 * bias[i1 * D + colg];
#pragma unroll
    for (int m = 0; m < 4; ++m) {
      const int rowb = m0 + wm + m * 16 + rq;
#pragma unroll
      for (int r = 0; r < 4; ++r)
        Ob[(size_t)(rowb + r) * D + colg] = acc[m][n][r] + bs;
    }
  }
}

extern "C" void kernel_launch(void* const* d_in, const int* in_sizes, int n_in,
                              void* d_out, int out_size, void* d_ws, size_t ws_size,
                              hipStream_t stream) {
  const float* tensor = (const float*)d_in[0];   // (2,2048,16,128) fp32
  const int*   sidx   = (const int*)d_in[1];     // (2,2) int32
  const float* sprob  = (const float*)d_in[2];   // (2,2) fp32
  const float* weight = (const float*)d_in[3];   // (16,2048,2048) fp32
  const float* bias   = (const float*)d_in[4];   // (16,2048) fp32
  float* out = (float*)d_out;                    // (2,2048,2048) fp32

  u16* xb = (u16*)d_ws;                          // (2,2048,2048) bf16, 16 MB
  u16* wt = xb + (size_t)BATCH * D * D;          // (2,2048,2048) bf16, 16 MB

  static bool inited = false;
  if (!inited) {
    (void)hipFuncSetAttribute((const void*)gemm_kernel,
                              hipFuncAttributeMaxDynamicSharedMemorySize,
                              3 * BUFSZ * 2);
    inited = true;
  }

  hipLaunchKernelGGL(prep_kernel, dim3(4096 + 512), dim3(256), 0, stream,
                     tensor, xb, weight, sidx, sprob, wt);
  hipLaunchKernelGGL(gemm_kernel, dim3(256), dim3(512),
                     3 * BUFSZ * 2, stream, xb, wt, bias, sidx, sprob, out);
}